// Round 1
// baseline (7466.262 us; speedup 1.0000x reference)
//
#include <hip/hip_runtime.h>
#include <math.h>

// ---------------- problem constants ----------------
#define BB     2
#define LSEG   64
#define HOP    256
#define TT     (LSEG*HOP)      // 16384
#define IN_CH  101
#define INNER  128
#define COND   81
#define LAYERS 5
#define KTAP   3
#define KH     64
#define COUT   256             // 2*INNER
#define RPL    (INNER*COUT*KTAP)   // 98304 rows per layer
#define KCH    (RPL*LAYERS)        // 491520
#define BCH    (COUT*LAYERS)       // 1280

// ws layout (floats):
//   bufA, bufB, bufC : BB*INNER*TT each (activation ping-pong)   3 x 16.78MB
//   h2buf            : BB*LSEG*KH     ([b][l][j], j contiguous)
//   biasbuf          : BB*LSEG*BCH    ([b][l][r])
//   kbuf             : BB*LSEG*RPL    ([b][l][r])  50.3MB, reused per layer
// total ~102 MB

// ---------------- fc: h = fc_W @ x + fc_b ----------------
__global__ __launch_bounds__(256) void k_fc(const float* __restrict__ x,
                                            const float* __restrict__ W,
                                            const float* __restrict__ bias,
                                            float* __restrict__ out) {
    int g = blockIdx.x*256 + threadIdx.x;      // over BB*TT
    int b = g / TT, t = g % TT;
    float xv[IN_CH];
    const float* xp = x + (size_t)b*IN_CH*TT + t;
#pragma unroll
    for (int c = 0; c < IN_CH; ++c) xv[c] = xp[(size_t)c*TT];
    float* op = out + (size_t)b*INNER*TT + t;
    for (int o = 0; o < INNER; ++o) {
        const float* wr = W + o*IN_CH;
        float a0 = bias[o], a1 = 0.f, a2 = 0.f, a3 = 0.f;
#pragma unroll
        for (int c = 0; c + 3 < IN_CH; c += 4) {
            a0 += wr[c]*xv[c]; a1 += wr[c+1]*xv[c+1];
            a2 += wr[c+2]*xv[c+2]; a3 += wr[c+3]*xv[c+3];
        }
        a0 += wr[100]*xv[100];
        op[(size_t)o*TT] = (a0+a1)+(a2+a3);
    }
}

// ---------------- kernel predictor (per block): h2 + bias head ----------------
__global__ __launch_bounds__(256) void k_pred(const float* __restrict__ cc,
    const float* __restrict__ iW, const float* __restrict__ ib,
    const float* __restrict__ r1W, const float* __restrict__ r1b,
    const float* __restrict__ r2W, const float* __restrict__ r2b,
    const float* __restrict__ bW, const float* __restrict__ bb,
    float* __restrict__ h2buf, float* __restrict__ biasbuf) {
    int part = blockIdx.x & 7;       // 8 parts split the bias rows
    int b    = blockIdx.x >> 3;
    __shared__ float cL[COND*LSEG];
    __shared__ float h1L[KH*LSEG];
    __shared__ float t1L[KH*LSEG];
    __shared__ float h2L[KH*LSEG];
    int tid = threadIdx.x;
    for (int idx = tid; idx < COND*LSEG; idx += 256)
        cL[idx] = cc[(size_t)b*COND*LSEG + idx];
    __syncthreads();
    // h1 = lrelu(conv5(c))
    for (int idx = tid; idx < KH*LSEG; idx += 256) {
        int l = idx & 63, o = idx >> 6;
        float acc = ib[o];
        for (int i = 0; i < COND; ++i) {
            const float* wrow = iW + (o*COND + i)*5;
            const float* crow = cL + i*LSEG;
#pragma unroll
            for (int k = 0; k < 5; ++k) {
                int ll = l + k - 2;
                if (ll >= 0 && ll < LSEG) acc += crow[ll]*wrow[k];
            }
        }
        h1L[idx] = acc >= 0.f ? acc : 0.1f*acc;   // [o][l]
    }
    __syncthreads();
    // t1 = lrelu(r1W @ h1 + r1b)
    for (int idx = tid; idx < KH*LSEG; idx += 256) {
        int l = idx & 63, o = idx >> 6;
        float acc = r1b[o];
        const float* wr = r1W + o*KH;
#pragma unroll
        for (int i = 0; i < KH; ++i) acc += wr[i]*h1L[i*LSEG + l];
        t1L[idx] = acc >= 0.f ? acc : 0.1f*acc;
    }
    __syncthreads();
    // h2 = h1 + (r2W @ t1 + r2b)
    for (int idx = tid; idx < KH*LSEG; idx += 256) {
        int l = idx & 63, o = idx >> 6;
        float acc = r2b[o];
        const float* wr = r2W + o*KH;
#pragma unroll
        for (int i = 0; i < KH; ++i) acc += wr[i]*t1L[i*LSEG + l];
        float h2 = h1L[idx] + acc;
        h2L[idx] = h2;
        if (part == 0) h2buf[((size_t)b*LSEG + l)*KH + o] = h2;  // [b][l][j]
    }
    __syncthreads();
    // bias head: biasbuf[b][l][r] = bW[r,:] @ h2[:,l] + bb[r]
    const int ROWS = BCH/8;  // 160
    for (int idx = tid; idx < ROWS*LSEG; idx += 256) {
        int l = idx & 63, rr = idx >> 6;
        int r = part*ROWS + rr;
        float acc = bb[r];
        const float* wr = bW + (size_t)r*KH;
#pragma unroll
        for (int j = 0; j < KH; ++j) acc += wr[j]*h2L[j*LSEG + l];
        biasbuf[((size_t)b*LSEG + l)*BCH + r] = acc;
    }
}

// ---------------- per-layer kernel generation: kbuf[b][l][r] = kW[r,:]@h2[b][l][:] + kb[r] ----------------
__global__ __launch_bounds__(256) void k_gen(const float* __restrict__ kW,
                                             const float* __restrict__ kb,
                                             const float* __restrict__ h2buf,
                                             float* __restrict__ kbuf) {
    int r = blockIdx.x*256 + threadIdx.x;     // r < RPL; kW/kb pre-offset to (block,layer)
    float w[KH];
    const float4* wp = (const float4*)(kW + (size_t)r*KH);
#pragma unroll
    for (int q = 0; q < KH/4; ++q) {
        float4 v = wp[q];
        w[4*q] = v.x; w[4*q+1] = v.y; w[4*q+2] = v.z; w[4*q+3] = v.w;
    }
    float kbv = kb[r];
    for (int bl = 0; bl < BB*LSEG; ++bl) {
        const float* h2 = h2buf + (size_t)bl*KH;   // uniform -> s_load
        float a0 = kbv, a1 = 0.f, a2 = 0.f, a3 = 0.f;
#pragma unroll
        for (int j = 0; j < KH; j += 4) {
            a0 += w[j]*h2[j]; a1 += w[j+1]*h2[j+1];
            a2 += w[j+2]*h2[j+2]; a3 += w[j+3]*h2[j+3];
        }
        kbuf[(size_t)bl*RPL + r] = (a0+a1)+(a2+a3);   // coalesced
    }
}

// ---------------- LVC layer + gating ----------------
// y[b,o,t] = bias[b,l,o] + sum_{c,k} x[b,c,t+(k-1)d] * kern[b,l,c,o,k], t = l*HOP + tid
// out[b,g,t] = sigmoid(y[g]) * tanh(y[g+128])
__global__ __launch_bounds__(256) void k_lvc(const float* __restrict__ xin,
                                             const float* __restrict__ kbuf,
                                             const float* __restrict__ biasbuf,
                                             float* __restrict__ xout,
                                             int dil, int layerIdx) {
    int wg  = blockIdx.x;          // BB*LSEG*4
    int oc  = wg & 3;              // 32-gate-channel chunk
    int l   = (wg >> 2) & 63;
    int b   = wg >> 8;
    int tid = threadIdx.x;         // t within segment
    int win = HOP + 2*dil;
    __shared__ float patch[32*288];      // 32 channels x (HOP+2*16) max

    const float* xb = xin + (size_t)b*INNER*TT;
    int t0 = l*HOP - dil;

    float accA[32], accB[32];
    const float* bias = biasbuf + ((size_t)b*LSEG + l)*BCH + layerIdx*COUT;
#pragma unroll
    for (int oi = 0; oi < 32; ++oi) {
        accA[oi] = bias[oc*32 + oi];
        accB[oi] = bias[oc*32 + oi + 128];
    }
    const float* kbase = kbuf + ((size_t)b*LSEG + l)*RPL;

    for (int ccg = 0; ccg < 4; ++ccg) {          // channel chunks of 32
        __syncthreads();
        for (int c = 0; c < 32; ++c) {
            const float* xc = xb + (size_t)(ccg*32 + c)*TT;
            float* pc = patch + c*288;
            for (int w = tid; w < win; w += 256) {
                int t = t0 + w;
                pc[w] = (t >= 0 && t < TT) ? xc[t] : 0.f;
            }
        }
        __syncthreads();
        for (int c = 0; c < 32; ++c) {
            int cg = ccg*32 + c;
            const float* pc = patch + c*288 + tid;
            float x0 = pc[0], x1 = pc[dil], x2 = pc[2*dil];
            const float* kr = kbase + (size_t)cg*(COUT*KTAP);   // uniform -> s_load
#pragma unroll
            for (int oi = 0; oi < 32; ++oi) {
                const float* ka = kr + (oc*32 + oi)*3;
                const float* kc = kr + (oc*32 + oi + 128)*3;
                accA[oi] += x0*ka[0] + x1*ka[1] + x2*ka[2];
                accB[oi] += x0*kc[0] + x1*kc[1] + x2*kc[2];
            }
        }
    }
    float* op = xout + (size_t)b*INNER*TT;
    int t = l*HOP + tid;
#pragma unroll
    for (int oi = 0; oi < 32; ++oi) {
        int g = oc*32 + oi;
        float a  = accA[oi];
        float bb = accB[oi];
        float s  = 1.f/(1.f + __expf(-a));
        float th = 2.f/(1.f + __expf(-2.f*bb)) - 1.f;
        op[(size_t)g*TT + t] = s*th;
    }
}

// ---------------- head: out = lc2 @ relu(lc1 @ relu(y0+y1) + b1) + b2 ----------------
__global__ __launch_bounds__(256) void k_head(const float* __restrict__ y0,
                                              const float* __restrict__ y1,
                                              const float* __restrict__ W1,
                                              const float* __restrict__ b1,
                                              const float* __restrict__ W2,
                                              const float* __restrict__ b2,
                                              float* __restrict__ out) {
    int g = blockIdx.x*256 + threadIdx.x;   // over BB*TT
    int b = g / TT, t = g % TT;
    float h[INNER];
    const float* p0 = y0 + (size_t)b*INNER*TT + t;
    const float* p1 = y1 + (size_t)b*INNER*TT + t;
#pragma unroll
    for (int c = 0; c < INNER; ++c) {
        float v = p0[(size_t)c*TT] + p1[(size_t)c*TT];
        h[c] = v > 0.f ? v : 0.f;
    }
    float acc = b2[0];
    for (int o = 0; o < INNER; ++o) {
        const float* wr = W1 + o*INNER;      // uniform -> s_load
        float z0 = b1[o], z1 = 0.f, z2 = 0.f, z3 = 0.f;
#pragma unroll
        for (int c = 0; c < INNER; c += 4) {
            z0 += wr[c]*h[c];   z1 += wr[c+1]*h[c+1];
            z2 += wr[c+2]*h[c+2]; z3 += wr[c+3]*h[c+3];
        }
        float z = (z0+z1)+(z2+z3);
        z = z > 0.f ? z : 0.f;
        acc += W2[o]*z;
    }
    out[g] = acc;
}

extern "C" void kernel_launch(void* const* d_in, const int* in_sizes, int n_in,
                              void* d_out, int out_size, void* d_ws, size_t ws_size,
                              hipStream_t stream) {
    const float* x    = (const float*)d_in[0];
    const float* c    = (const float*)d_in[1];
    const float* fcW  = (const float*)d_in[2];
    const float* fcb  = (const float*)d_in[3];
    const float* inpW = (const float*)d_in[4];
    const float* inpb = (const float*)d_in[5];
    const float* r1W  = (const float*)d_in[6];
    const float* r1b  = (const float*)d_in[7];
    const float* r2W  = (const float*)d_in[8];
    const float* r2b  = (const float*)d_in[9];
    const float* kW   = (const float*)d_in[10];
    const float* kb   = (const float*)d_in[11];
    const float* bW   = (const float*)d_in[12];
    const float* bb   = (const float*)d_in[13];
    const float* l1W  = (const float*)d_in[14];
    const float* l1b  = (const float*)d_in[15];
    const float* l2W  = (const float*)d_in[16];
    const float* l2b  = (const float*)d_in[17];

    float* ws   = (float*)d_ws;
    size_t NT   = (size_t)BB*INNER*TT;
    float* bufA = ws;
    float* bufB = bufA + NT;
    float* bufC = bufB + NT;
    float* h2buf   = bufC + NT;
    float* biasbuf = h2buf + (size_t)BB*LSEG*KH;
    float* kbuf    = biasbuf + (size_t)BB*LSEG*BCH;

    k_fc<<<BB*TT/256, 256, 0, stream>>>(x, fcW, fcb, bufA);

    for (int n = 0; n < 2; ++n) {
        k_pred<<<16, 256, 0, stream>>>(c,
            inpW + (size_t)n*KH*COND*5, inpb + n*KH,
            r1W + n*KH*KH, r1b + n*KH,
            r2W + n*KH*KH, r2b + n*KH,
            bW + (size_t)n*BCH*KH, bb + n*BCH,
            h2buf, biasbuf);
        float* pin = (n == 0) ? bufA : bufB;   // block1 consumes y0 (bufB)
        float* s0  = (n == 0) ? bufB : bufC;
        float* s1  = (n == 0) ? bufC : bufA;
        float* cin = pin;
        for (int i = 0; i < LAYERS; ++i) {
            k_gen<<<RPL/256, 256, 0, stream>>>(
                kW + ((size_t)n*KCH + (size_t)i*RPL)*KH,
                kb + (size_t)n*KCH + (size_t)i*RPL,
                h2buf, kbuf);
            float* cout_ = (i % 2 == 0) ? s0 : s1;
            k_lvc<<<BB*LSEG*4, 256, 0, stream>>>(cin, kbuf, biasbuf, cout_, 1 << i, i);
            cin = cout_;
        }
    }
    // y0 = bufB, y1 = bufC
    k_head<<<BB*TT/256, 256, 0, stream>>>(bufB, bufC, l1W, l1b, l2W, l2b, (float*)d_out);
}

// Round 2
// 5081.992 us; speedup vs baseline: 1.4692x; 1.4692x over previous
//
#include <hip/hip_runtime.h>
#include <math.h>

// ---------------- problem constants ----------------
#define BB     2
#define LSEG   64
#define HOP    256
#define TT     (LSEG*HOP)      // 16384
#define IN_CH  101
#define INNER  128
#define COND   81
#define LAYERS 5
#define KTAP   3
#define KH     64
#define COUT   256             // 2*INNER
#define RPL    (INNER*COUT*KTAP)   // 98304 rows per layer
#define KCH    (RPL*LAYERS)        // 491520
#define BCH    (COUT*LAYERS)       // 1280

// ---------------- fc: h = fc_W @ x + fc_b (o split over 2 block-halves) ----------------
__global__ __launch_bounds__(256) void k_fc(const float* __restrict__ x,
                                            const float* __restrict__ W,
                                            const float* __restrict__ bias,
                                            float* __restrict__ out) {
    int half = blockIdx.x & 1;
    int g = (blockIdx.x >> 1)*256 + threadIdx.x;   // over BB*TT
    int b = g / TT, t = g % TT;
    float xv[IN_CH];
    const float* xp = x + (size_t)b*IN_CH*TT + t;
#pragma unroll
    for (int c = 0; c < IN_CH; ++c) xv[c] = xp[(size_t)c*TT];
    float* op = out + (size_t)b*INNER*TT + t;
    int o0 = half*64;
    for (int o = o0; o < o0 + 64; ++o) {
        const float* wr = W + o*IN_CH;
        float a0 = bias[o], a1 = 0.f, a2 = 0.f, a3 = 0.f;
#pragma unroll
        for (int c = 0; c + 3 < IN_CH; c += 4) {
            a0 += wr[c]*xv[c]; a1 += wr[c+1]*xv[c+1];
            a2 += wr[c+2]*xv[c+2]; a3 += wr[c+3]*xv[c+3];
        }
        a0 += wr[100]*xv[100];
        op[(size_t)o*TT] = (a0+a1)+(a2+a3);
    }
}

// ---------------- predictor stage 1: h1 = lrelu(conv5(c)), weights in LDS ----------------
// grid = BB*8, block (b, og): computes h1 for o in [og*8, og*8+8)
__global__ __launch_bounds__(256) void k_h1(const float* __restrict__ cc,
                                            const float* __restrict__ iW,
                                            const float* __restrict__ ib,
                                            float* __restrict__ h1buf) {
    int og = blockIdx.x & 7;
    int b  = blockIdx.x >> 3;
    __shared__ float cL[COND*LSEG];        // 5184 floats
    __shared__ float wL[8*COND*5];         // 3240 floats
    int tid = threadIdx.x;
    for (int idx = tid; idx < COND*LSEG; idx += 256)
        cL[idx] = cc[(size_t)b*COND*LSEG + idx];
    const float* wsrc = iW + (size_t)og*8*COND*5;
    for (int idx = tid; idx < 8*COND*5; idx += 256)
        wL[idx] = wsrc[idx];
    __syncthreads();
#pragma unroll
    for (int rep = 0; rep < 2; ++rep) {
        int idx = rep*256 + tid;           // 512 outputs: 8 o x 64 l
        int ol = idx >> 6;                 // local o (wave-uniform, LDS broadcast)
        int l  = idx & 63;
        int o  = og*8 + ol;
        float acc = ib[o];
        const float* wrow = wL + ol*COND*5;
        for (int i = 0; i < COND; ++i) {
            const float* crow = cL + i*LSEG;
            const float* w5 = wrow + i*5;
#pragma unroll
            for (int k = 0; k < 5; ++k) {
                int ll = l + k - 2;
                if (ll >= 0 && ll < LSEG) acc += crow[ll]*w5[k];
            }
        }
        h1buf[((size_t)b*KH + o)*LSEG + l] = acc >= 0.f ? acc : 0.1f*acc;
    }
}

// ---------------- predictor stage 2: h2 = h1 + r2W@lrelu(r1W@h1+r1b)+r2b, all LDS ----------------
// grid = BB
__global__ __launch_bounds__(256) void k_h2t(const float* __restrict__ h1buf,
                                             const float* __restrict__ r1W,
                                             const float* __restrict__ r1b,
                                             const float* __restrict__ r2W,
                                             const float* __restrict__ r2b,
                                             float* __restrict__ h2buf) {
    int b = blockIdx.x;
    __shared__ float h1L[KH*LSEG];   // [i][l]
    __shared__ float t1L[KH*LSEG];
    __shared__ float wL[KH*KH];
    int tid = threadIdx.x;
    for (int idx = tid; idx < KH*LSEG; idx += 256)
        h1L[idx] = h1buf[(size_t)b*KH*LSEG + idx];
    for (int idx = tid; idx < KH*KH; idx += 256)
        wL[idx] = r1W[idx];
    __syncthreads();
#pragma unroll
    for (int rep = 0; rep < 16; ++rep) {
        int idx = rep*256 + tid;
        int o = idx >> 6, l = idx & 63;
        float acc = r1b[o];
        const float* wr = wL + o*KH;
#pragma unroll
        for (int i = 0; i < KH; ++i) acc += wr[i]*h1L[i*LSEG + l];
        t1L[idx] = acc >= 0.f ? acc : 0.1f*acc;
    }
    __syncthreads();
    for (int idx = tid; idx < KH*KH; idx += 256)
        wL[idx] = r2W[idx];
    __syncthreads();
#pragma unroll
    for (int rep = 0; rep < 16; ++rep) {
        int idx = rep*256 + tid;
        int o = idx >> 6, l = idx & 63;
        float acc = r2b[o];
        const float* wr = wL + o*KH;
#pragma unroll
        for (int i = 0; i < KH; ++i) acc += wr[i]*t1L[i*LSEG + l];
        // h2buf layout [b][l][j]
        h2buf[((size_t)b*LSEG + l)*KH + o] = h1L[o*LSEG + l] + acc;
    }
}

// ---------------- per-layer kernel generation + (layer0) bias head ----------------
// main: kbuf[b][l][r] = kW[r,:]@h2[b][l][:] + kb[r]        (blocks 0..383)
// bias: biasbuf[b][l][rb] = bW[rb,:]@h2[b][l][:] + bb[rb]  (blocks 384..393, only if bW)
__global__ __launch_bounds__(256) void k_gen(const float* __restrict__ kW,
                                             const float* __restrict__ kb,
                                             const float* __restrict__ h2buf,
                                             float* __restrict__ kbuf,
                                             const float* __restrict__ bW,
                                             const float* __restrict__ bb,
                                             float* __restrict__ biasbuf) {
    if (blockIdx.x >= RPL/256) {
        if (bW == nullptr) return;
        int tg = (blockIdx.x - RPL/256)*256 + threadIdx.x;   // 0..2559
        int b  = __builtin_amdgcn_readfirstlane(tg / BCH);   // uniform per wave
        int rb = tg % BCH;
        float w[KH];
        const float4* wp = (const float4*)(bW + (size_t)rb*KH);
#pragma unroll
        for (int q = 0; q < KH/4; ++q) {
            float4 v = wp[q];
            w[4*q] = v.x; w[4*q+1] = v.y; w[4*q+2] = v.z; w[4*q+3] = v.w;
        }
        float bv = bb[rb];
        for (int l = 0; l < LSEG; ++l) {
            const float* h2 = h2buf + ((size_t)b*LSEG + l)*KH;   // uniform -> s_load
            float a0 = bv, a1 = 0.f, a2 = 0.f, a3 = 0.f;
#pragma unroll
            for (int j = 0; j < KH; j += 4) {
                a0 += w[j]*h2[j]; a1 += w[j+1]*h2[j+1];
                a2 += w[j+2]*h2[j+2]; a3 += w[j+3]*h2[j+3];
            }
            biasbuf[((size_t)b*LSEG + l)*BCH + rb] = (a0+a1)+(a2+a3);
        }
        return;
    }
    int r = blockIdx.x*256 + threadIdx.x;     // r < RPL
    float w[KH];
    const float4* wp = (const float4*)(kW + (size_t)r*KH);
#pragma unroll
    for (int q = 0; q < KH/4; ++q) {
        float4 v = wp[q];
        w[4*q] = v.x; w[4*q+1] = v.y; w[4*q+2] = v.z; w[4*q+3] = v.w;
    }
    float kbv = kb[r];
    for (int bl = 0; bl < BB*LSEG; bl += 2) {     // unroll 2: two s_load batches in flight
        const float* h2a = h2buf + (size_t)bl*KH;
        const float* h2b = h2a + KH;
        float a0 = kbv, a1 = 0.f, a2 = 0.f, a3 = 0.f;
        float c0 = kbv, c1 = 0.f, c2 = 0.f, c3 = 0.f;
#pragma unroll
        for (int j = 0; j < KH; j += 4) {
            a0 += w[j]*h2a[j];   a1 += w[j+1]*h2a[j+1];
            a2 += w[j+2]*h2a[j+2]; a3 += w[j+3]*h2a[j+3];
            c0 += w[j]*h2b[j];   c1 += w[j+1]*h2b[j+1];
            c2 += w[j+2]*h2b[j+2]; c3 += w[j+3]*h2b[j+3];
        }
        kbuf[(size_t)bl*RPL + r]     = (a0+a1)+(a2+a3);
        kbuf[(size_t)(bl+1)*RPL + r] = (c0+c1)+(c2+c3);
    }
}

// ---------------- LVC layer + gating ----------------
// grid = BB*LSEG*8 ; WG (b, l, oc) computes 16 gate channels (oc*16..+15)
__global__ __launch_bounds__(256) void k_lvc(const float* __restrict__ xin,
                                             const float* __restrict__ kbuf,
                                             const float* __restrict__ biasbuf,
                                             float* __restrict__ xout,
                                             int dil, int layerIdx) {
    int wg  = blockIdx.x;
    int oc  = wg & 7;              // 16-gate-channel chunk
    int l   = (wg >> 3) & 63;
    int b   = wg >> 9;
    int tid = threadIdx.x;         // t within segment
    int win = HOP + 2*dil;
    __shared__ float patch[32*288];      // 32 channels x (HOP+2*16) max

    const float* xb = xin + (size_t)b*INNER*TT;
    int t0 = l*HOP - dil;

    float accA[16], accB[16];
    const float* bias = biasbuf + ((size_t)b*LSEG + l)*BCH + layerIdx*COUT;
#pragma unroll
    for (int oi = 0; oi < 16; ++oi) {
        accA[oi] = bias[oc*16 + oi];
        accB[oi] = bias[oc*16 + oi + 128];
    }
    const float* kbase = kbuf + ((size_t)b*LSEG + l)*RPL;

    for (int ccg = 0; ccg < 4; ++ccg) {          // channel chunks of 32
        __syncthreads();
        for (int c = 0; c < 32; ++c) {
            const float* xc = xb + (size_t)(ccg*32 + c)*TT;
            float* pc = patch + c*288;
            for (int w = tid; w < win; w += 256) {
                int t = t0 + w;
                pc[w] = (t >= 0 && t < TT) ? xc[t] : 0.f;
            }
        }
        __syncthreads();
#pragma unroll 2
        for (int c = 0; c < 32; ++c) {
            int cg = ccg*32 + c;
            const float* pc = patch + c*288 + tid;
            float x0 = pc[0], x1 = pc[dil], x2 = pc[2*dil];
            const float* kr = kbase + (size_t)cg*(COUT*KTAP);   // uniform -> s_load
#pragma unroll
            for (int oi = 0; oi < 16; ++oi) {
                const float* ka = kr + (oc*16 + oi)*3;
                const float* kc = kr + (oc*16 + oi + 128)*3;
                accA[oi] += x0*ka[0] + x1*ka[1] + x2*ka[2];
                accB[oi] += x0*kc[0] + x1*kc[1] + x2*kc[2];
            }
        }
    }
    float* op = xout + (size_t)b*INNER*TT;
    int t = l*HOP + tid;
#pragma unroll
    for (int oi = 0; oi < 16; ++oi) {
        int g = oc*16 + oi;
        float a  = accA[oi];
        float bv = accB[oi];
        float s  = 1.f/(1.f + __expf(-a));
        float th = 2.f/(1.f + __expf(-2.f*bv)) - 1.f;
        op[(size_t)g*TT + t] = s*th;
    }
}

// ---------------- head: out = lc2 @ relu(lc1 @ relu(y0+y1) + b1) + b2 ----------------
__global__ __launch_bounds__(256) void k_head(const float* __restrict__ y0,
                                              const float* __restrict__ y1,
                                              const float* __restrict__ W1,
                                              const float* __restrict__ b1,
                                              const float* __restrict__ W2,
                                              const float* __restrict__ b2,
                                              float* __restrict__ out) {
    int g = blockIdx.x*256 + threadIdx.x;   // over BB*TT
    int b = g / TT, t = g % TT;
    float h[INNER];
    const float* p0 = y0 + (size_t)b*INNER*TT + t;
    const float* p1 = y1 + (size_t)b*INNER*TT + t;
#pragma unroll
    for (int c = 0; c < INNER; ++c) {
        float v = p0[(size_t)c*TT] + p1[(size_t)c*TT];
        h[c] = v > 0.f ? v : 0.f;
    }
    float acc = b2[0];
    for (int o = 0; o < INNER; ++o) {
        const float* wr = W1 + o*INNER;      // uniform -> s_load
        float z0 = b1[o], z1 = 0.f, z2 = 0.f, z3 = 0.f;
#pragma unroll
        for (int c = 0; c < INNER; c += 4) {
            z0 += wr[c]*h[c];   z1 += wr[c+1]*h[c+1];
            z2 += wr[c+2]*h[c+2]; z3 += wr[c+3]*h[c+3];
        }
        float z = (z0+z1)+(z2+z3);
        z = z > 0.f ? z : 0.f;
        acc += W2[o]*z;
    }
    out[g] = acc;
}

extern "C" void kernel_launch(void* const* d_in, const int* in_sizes, int n_in,
                              void* d_out, int out_size, void* d_ws, size_t ws_size,
                              hipStream_t stream) {
    const float* x    = (const float*)d_in[0];
    const float* c    = (const float*)d_in[1];
    const float* fcW  = (const float*)d_in[2];
    const float* fcb  = (const float*)d_in[3];
    const float* inpW = (const float*)d_in[4];
    const float* inpb = (const float*)d_in[5];
    const float* r1W  = (const float*)d_in[6];
    const float* r1b  = (const float*)d_in[7];
    const float* r2W  = (const float*)d_in[8];
    const float* r2b  = (const float*)d_in[9];
    const float* kW   = (const float*)d_in[10];
    const float* kb   = (const float*)d_in[11];
    const float* bW   = (const float*)d_in[12];
    const float* bb   = (const float*)d_in[13];
    const float* l1W  = (const float*)d_in[14];
    const float* l1b  = (const float*)d_in[15];
    const float* l2W  = (const float*)d_in[16];
    const float* l2b  = (const float*)d_in[17];

    float* ws   = (float*)d_ws;
    size_t NT   = (size_t)BB*INNER*TT;
    float* bufA = ws;
    float* bufB = bufA + NT;
    float* bufC = bufB + NT;
    float* h2buf   = bufC + NT;                         // BB*LSEG*KH
    float* biasbuf = h2buf + (size_t)BB*LSEG*KH;        // BB*LSEG*BCH
    float* kbuf    = biasbuf + (size_t)BB*LSEG*BCH;     // BB*LSEG*RPL
    float* h1buf   = kbuf + (size_t)BB*LSEG*RPL;        // BB*KH*LSEG

    k_fc<<<BB*TT/256*2, 256, 0, stream>>>(x, fcW, fcb, bufA);

    for (int n = 0; n < 2; ++n) {
        k_h1<<<BB*8, 256, 0, stream>>>(c, inpW + (size_t)n*KH*COND*5, inpb + n*KH, h1buf);
        k_h2t<<<BB, 256, 0, stream>>>(h1buf,
            r1W + n*KH*KH, r1b + n*KH,
            r2W + n*KH*KH, r2b + n*KH, h2buf);
        float* pin = (n == 0) ? bufA : bufB;   // block1 consumes y0 (bufB)
        float* s0  = (n == 0) ? bufB : bufC;
        float* s1  = (n == 0) ? bufC : bufA;
        float* cin = pin;
        for (int i = 0; i < LAYERS; ++i) {
            int gblocks = (i == 0) ? (RPL/256 + (BB*BCH)/256) : (RPL/256);
            k_gen<<<gblocks, 256, 0, stream>>>(
                kW + ((size_t)n*KCH + (size_t)i*RPL)*KH,
                kb + (size_t)n*KCH + (size_t)i*RPL,
                h2buf, kbuf,
                (i == 0) ? (bW + (size_t)n*BCH*KH) : nullptr,
                bb + (size_t)n*BCH,
                biasbuf);
            float* cout_ = (i % 2 == 0) ? s0 : s1;
            k_lvc<<<BB*LSEG*8, 256, 0, stream>>>(cin, kbuf, biasbuf, cout_, 1 << i, i);
            cin = cout_;
        }
    }
    // y0 = bufB, y1 = bufC
    k_head<<<BB*TT/256, 256, 0, stream>>>(bufB, bufC, l1W, l1b, l2W, l2b, (float*)d_out);
}

// Round 3
// 1974.276 us; speedup vs baseline: 3.7818x; 2.5741x over previous
//
#include <hip/hip_runtime.h>
#include <math.h>

// ---------------- problem constants ----------------
#define BB     2
#define LSEG   64
#define HOP    256
#define TT     (LSEG*HOP)      // 16384
#define IN_CH  101
#define INNER  128
#define COND   81
#define LAYERS 5
#define KTAP   3
#define KH     64
#define COUT   256             // 2*INNER
#define RPL    (INNER*COUT*KTAP)   // 98304 rows per layer
#define KCH    (RPL*LAYERS)        // 491520
#define BCH    (COUT*LAYERS)       // 1280
#define NBL    (BB*LSEG)           // 128

typedef _Float16 f16;
typedef _Float16 f16x2 __attribute__((ext_vector_type(2)));
typedef _Float16 f16x8 __attribute__((ext_vector_type(8)));
typedef float    f32x4 __attribute__((ext_vector_type(4)));

// ---------------- fc: h = fc_W @ x + fc_b -> f16 activations ----------------
__global__ __launch_bounds__(256) void k_fc(const float* __restrict__ x,
                                            const float* __restrict__ W,
                                            const float* __restrict__ bias,
                                            f16* __restrict__ out) {
    int half = blockIdx.x & 1;
    int g = (blockIdx.x >> 1)*256 + threadIdx.x;   // over BB*TT
    int b = g / TT, t = g % TT;
    float xv[IN_CH];
    const float* xp = x + (size_t)b*IN_CH*TT + t;
#pragma unroll
    for (int c = 0; c < IN_CH; ++c) xv[c] = xp[(size_t)c*TT];
    f16* op = out + (size_t)b*INNER*TT + t;
    int o0 = half*64;
    for (int o = o0; o < o0 + 64; ++o) {
        const float* wr = W + o*IN_CH;
        float a0 = bias[o], a1 = 0.f, a2 = 0.f, a3 = 0.f;
#pragma unroll
        for (int c = 0; c + 3 < IN_CH; c += 4) {
            a0 += wr[c]*xv[c]; a1 += wr[c+1]*xv[c+1];
            a2 += wr[c+2]*xv[c+2]; a3 += wr[c+3]*xv[c+3];
        }
        a0 += wr[100]*xv[100];
        op[(size_t)o*TT] = (f16)((a0+a1)+(a2+a3));
    }
}

// ---------------- predictor stage 1: h1 = lrelu(conv5(c)) ----------------
__global__ __launch_bounds__(256) void k_h1(const float* __restrict__ cc,
                                            const float* __restrict__ iW,
                                            const float* __restrict__ ib,
                                            float* __restrict__ h1buf) {
    int og = blockIdx.x & 7;
    int b  = blockIdx.x >> 3;
    __shared__ float cL[COND*LSEG];
    __shared__ float wL[8*COND*5];
    int tid = threadIdx.x;
    for (int idx = tid; idx < COND*LSEG; idx += 256)
        cL[idx] = cc[(size_t)b*COND*LSEG + idx];
    const float* wsrc = iW + (size_t)og*8*COND*5;
    for (int idx = tid; idx < 8*COND*5; idx += 256)
        wL[idx] = wsrc[idx];
    __syncthreads();
#pragma unroll
    for (int rep = 0; rep < 2; ++rep) {
        int idx = rep*256 + tid;
        int ol = idx >> 6, l = idx & 63;
        int o  = og*8 + ol;
        float acc = ib[o];
        const float* wrow = wL + ol*COND*5;
        for (int i = 0; i < COND; ++i) {
            const float* crow = cL + i*LSEG;
            const float* w5 = wrow + i*5;
#pragma unroll
            for (int k = 0; k < 5; ++k) {
                int ll = l + k - 2;
                if (ll >= 0 && ll < LSEG) acc += crow[ll]*w5[k];
            }
        }
        h1buf[((size_t)b*KH + o)*LSEG + l] = acc >= 0.f ? acc : 0.1f*acc;
    }
}

// ---------------- predictor stage 2: h2 (f32 for bias head, f16 for k_gen) ----------------
__global__ __launch_bounds__(256) void k_h2t(const float* __restrict__ h1buf,
                                             const float* __restrict__ r1W,
                                             const float* __restrict__ r1b,
                                             const float* __restrict__ r2W,
                                             const float* __restrict__ r2b,
                                             float* __restrict__ h2buf,
                                             f16* __restrict__ h2h) {
    int b = blockIdx.x;
    __shared__ float h1L[KH*LSEG];
    __shared__ float t1L[KH*LSEG];
    __shared__ float wL[KH*KH];
    int tid = threadIdx.x;
    for (int idx = tid; idx < KH*LSEG; idx += 256)
        h1L[idx] = h1buf[(size_t)b*KH*LSEG + idx];
    for (int idx = tid; idx < KH*KH; idx += 256)
        wL[idx] = r1W[idx];
    __syncthreads();
#pragma unroll
    for (int rep = 0; rep < 16; ++rep) {
        int idx = rep*256 + tid;
        int o = idx >> 6, l = idx & 63;
        float acc = r1b[o];
        const float* wr = wL + o*KH;
#pragma unroll
        for (int i = 0; i < KH; ++i) acc += wr[i]*h1L[i*LSEG + l];
        t1L[idx] = acc >= 0.f ? acc : 0.1f*acc;
    }
    __syncthreads();
    for (int idx = tid; idx < KH*KH; idx += 256)
        wL[idx] = r2W[idx];
    __syncthreads();
#pragma unroll
    for (int rep = 0; rep < 16; ++rep) {
        int idx = rep*256 + tid;
        int o = idx >> 6, l = idx & 63;
        float acc = r2b[o];
        const float* wr = wL + o*KH;
#pragma unroll
        for (int i = 0; i < KH; ++i) acc += wr[i]*t1L[i*LSEG + l];
        float h2 = h1L[o*LSEG + l] + acc;
        h2buf[((size_t)b*LSEG + l)*KH + o] = h2;           // [bl][o] f32
        h2h  [((size_t)b*LSEG + l)*KH + o] = (f16)h2;      // [bl][o] f16
    }
}

// ---------------- kernel generation (f16, MFMA-friendly layout) + layer0 bias head ----
// kbuf[bl][o'][kk'] f16, o' = gate-interleave(o), kk' = tap*128 + c
// grid: 768 blocks = (tap 0..2) x (o 0..255); threads = (blh 0..1) x (c 0..127)
__global__ __launch_bounds__(256) void k_gen(const float* __restrict__ kW,
                                             const float* __restrict__ kb,
                                             const f16*   __restrict__ h2h,
                                             f16*         __restrict__ kbuf,
                                             const float* __restrict__ bW,
                                             const float* __restrict__ bb,
                                             float* __restrict__ biasbuf,
                                             const float* __restrict__ h2buf) {
    if (blockIdx.x >= 768) {
        if (bW == nullptr) return;
        int tg = (blockIdx.x - 768)*256 + threadIdx.x;       // 0..2559
        int b  = __builtin_amdgcn_readfirstlane(tg / BCH);
        int rb = tg % BCH;
        float w[KH];
        const float4* wp = (const float4*)(bW + (size_t)rb*KH);
#pragma unroll
        for (int q = 0; q < KH/4; ++q) {
            float4 v = wp[q];
            w[4*q] = v.x; w[4*q+1] = v.y; w[4*q+2] = v.z; w[4*q+3] = v.w;
        }
        float bv = bb[rb];
        for (int l = 0; l < LSEG; ++l) {
            const float* h2 = h2buf + ((size_t)b*LSEG + l)*KH;
            float a0 = bv, a1 = 0.f, a2 = 0.f, a3 = 0.f;
#pragma unroll
            for (int j = 0; j < KH; j += 4) {
                a0 += w[j]*h2[j]; a1 += w[j+1]*h2[j+1];
                a2 += w[j+2]*h2[j+2]; a3 += w[j+3]*h2[j+3];
            }
            biasbuf[((size_t)b*LSEG + l)*BCH + rb] = (a0+a1)+(a2+a3);
        }
        return;
    }
    int tap = blockIdx.x >> 8;          // 0..2
    int o   = blockIdx.x & 255;
    int c   = threadIdx.x & 127;
    int blh = threadIdx.x >> 7;         // bl-half (wave-uniform)
    int r   = (c*COUT + o)*KTAP + tap;
    // load+convert weight row to f16 pairs (32 VGPRs)
    f16x2 wh[32];
    const float4* wp = (const float4*)(kW + (size_t)r*KH);
#pragma unroll
    for (int q = 0; q < 16; ++q) {
        float4 v = wp[q];
        wh[2*q]   = f16x2{(f16)v.x, (f16)v.y};
        wh[2*q+1] = f16x2{(f16)v.z, (f16)v.w};
    }
    float kbv = kb[r];
    int op = (o < 128) ? 2*o : 2*(o-128) + 1;
    size_t obase = (size_t)op*384 + (size_t)tap*128 + c;
    for (int bl = blh*64; bl < blh*64 + 64; ++bl) {
        const f16x2* h2p = (const f16x2*)(h2h + (size_t)bl*KH);   // wave-uniform -> s_load
        float a0 = kbv, a1 = 0.f, a2 = 0.f, a3 = 0.f;
#pragma unroll
        for (int q = 0; q < 8; ++q) {
            a0 = __builtin_amdgcn_fdot2(wh[4*q],   h2p[4*q],   a0, false);
            a1 = __builtin_amdgcn_fdot2(wh[4*q+1], h2p[4*q+1], a1, false);
            a2 = __builtin_amdgcn_fdot2(wh[4*q+2], h2p[4*q+2], a2, false);
            a3 = __builtin_amdgcn_fdot2(wh[4*q+3], h2p[4*q+3], a3, false);
        }
        kbuf[(size_t)bl*RPL + obase] = (f16)((a0+a1)+(a2+a3));
    }
}

// ---------------- LVC layer via MFMA + fused gating ----------------
// grid = BB*LSEG*4; WG (b,l,oq) computes C[64 o' x 256 t] for one (b,l)
// C = kern[o'][kk'] @ X[kk'][t];  kk' = tap*128 + c;  gating fused via o'-interleave
template<int DIL>
__global__ __launch_bounds__(256) void k_lvc(const f16* __restrict__ xin,
                                             const f16* __restrict__ kbuf,
                                             const float* __restrict__ biasbuf,
                                             f16* __restrict__ xout,
                                             int layerIdx) {
    constexpr int WIN = 256 + 2*DIL;
    int wg  = blockIdx.x;
    int o0  = (wg & 3)*64;         // o'-range base
    int l   = (wg >> 2) & 63;
    int b   = wg >> 8;
    int bl  = b*LSEG + l;
    int tid = threadIdx.x;
    int w   = tid >> 6;            // wave id 0..3
    int lane = tid & 63;
    int quad = lane >> 4;
    int n16  = lane & 15;
    int wo = (w & 1)*32;           // wave o'-offset
    int wt = (w >> 1)*128;         // wave t-offset

    __shared__ f16 As[64*32];          // [o'_local][kk 32]
    __shared__ f16 xwin[288*32];       // [tw][c]  (transposed window)

    // accumulator init with bias (gate-interleaved rows)
    const float* bias_l = biasbuf + (size_t)bl*BCH + layerIdx*COUT;
    f32x4 acc[2][8];
#pragma unroll
    for (int j = 0; j < 2; ++j) {
        int g0 = (o0 + wo + j*16 + quad*4) >> 1;
        f32x4 ini;
        ini[0] = bias_l[g0];       ini[1] = bias_l[g0 + 128];
        ini[2] = bias_l[g0 + 1];   ini[3] = bias_l[g0 + 1 + 128];
#pragma unroll
        for (int tt = 0; tt < 8; ++tt) acc[j][tt] = ini;
    }

    const f16* xb = xin + (size_t)b*INNER*TT;
    const f16* kbl = kbuf + (size_t)bl*RPL + (size_t)o0*384;

    for (int cb = 0; cb < 4; ++cb) {
        // stage x window for this c-block (covers all 3 taps), transposed [tw][c]
        for (int idx = tid; idx < 32*WIN; idx += 256) {
            int c  = idx / WIN;
            int tw = idx - c*WIN;
            int gt = l*256 - DIL + tw;
            f16 v = (gt >= 0 && gt < TT) ? xb[(size_t)(cb*32 + c)*TT + gt] : (f16)0.f;
            xwin[tw*32 + c] = v;
        }
        for (int tap = 0; tap < 3; ++tap) {
            // stage A chunk [64 o' x 32 kk]
            {
                int o_l = tid >> 2, q = tid & 3;
                int kkbase = tap*128 + cb*32;
                f16x8 v = *(const f16x8*)&kbl[(size_t)o_l*384 + kkbase + q*8];
                *(f16x8*)&As[o_l*32 + q*8] = v;
            }
            __syncthreads();
            f16x8 af0 = *(const f16x8*)&As[(wo + n16)*32 + quad*8];
            f16x8 af1 = *(const f16x8*)&As[(wo + 16 + n16)*32 + quad*8];
#pragma unroll
            for (int tt = 0; tt < 8; ++tt) {
                int trow = wt + tt*16 + n16 + tap*DIL;
                f16x8 bf = *(const f16x8*)&xwin[trow*32 + quad*8];
                acc[0][tt] = __builtin_amdgcn_mfma_f32_16x16x32_f16(af0, bf, acc[0][tt], 0, 0, 0);
                acc[1][tt] = __builtin_amdgcn_mfma_f32_16x16x32_f16(af1, bf, acc[1][tt], 0, 0, 0);
            }
            __syncthreads();
        }
    }
    // epilogue: fused gating, f16 stores
    f16* ob = xout + (size_t)b*INNER*TT + l*256;
#pragma unroll
    for (int j = 0; j < 2; ++j) {
        int g0 = (o0 + wo + j*16 + quad*4) >> 1;
#pragma unroll
        for (int tt = 0; tt < 8; ++tt) {
            int tloc = wt + tt*16 + n16;
            f32x4 a = acc[j][tt];
            float s0  = 1.f/(1.f + __expf(-a[0]));
            float th0 = 2.f/(1.f + __expf(-2.f*a[1])) - 1.f;
            float s1  = 1.f/(1.f + __expf(-a[2]));
            float th1 = 2.f/(1.f + __expf(-2.f*a[3])) - 1.f;
            ob[(size_t)g0*TT + tloc]     = (f16)(s0*th0);
            ob[(size_t)(g0+1)*TT + tloc] = (f16)(s1*th1);
        }
    }
}

// ---------------- head ----------------
__global__ __launch_bounds__(256) void k_head(const f16* __restrict__ y0,
                                              const f16* __restrict__ y1,
                                              const float* __restrict__ W1,
                                              const float* __restrict__ b1,
                                              const float* __restrict__ W2,
                                              const float* __restrict__ b2,
                                              float* __restrict__ out) {
    int g = blockIdx.x*256 + threadIdx.x;
    int b = g / TT, t = g % TT;
    float h[INNER];
    const f16* p0 = y0 + (size_t)b*INNER*TT + t;
    const f16* p1 = y1 + (size_t)b*INNER*TT + t;
#pragma unroll
    for (int c = 0; c < INNER; ++c) {
        float v = (float)p0[(size_t)c*TT] + (float)p1[(size_t)c*TT];
        h[c] = v > 0.f ? v : 0.f;
    }
    float acc = b2[0];
    for (int o = 0; o < INNER; ++o) {
        const float* wr = W1 + o*INNER;
        float z0 = b1[o], z1 = 0.f, z2 = 0.f, z3 = 0.f;
#pragma unroll
        for (int c = 0; c < INNER; c += 4) {
            z0 += wr[c]*h[c];   z1 += wr[c+1]*h[c+1];
            z2 += wr[c+2]*h[c+2]; z3 += wr[c+3]*h[c+3];
        }
        float z = (z0+z1)+(z2+z3);
        z = z > 0.f ? z : 0.f;
        acc += W2[o]*z;
    }
    out[g] = acc;
}

extern "C" void kernel_launch(void* const* d_in, const int* in_sizes, int n_in,
                              void* d_out, int out_size, void* d_ws, size_t ws_size,
                              hipStream_t stream) {
    const float* x    = (const float*)d_in[0];
    const float* c    = (const float*)d_in[1];
    const float* fcW  = (const float*)d_in[2];
    const float* fcb  = (const float*)d_in[3];
    const float* inpW = (const float*)d_in[4];
    const float* inpb = (const float*)d_in[5];
    const float* r1W  = (const float*)d_in[6];
    const float* r1b  = (const float*)d_in[7];
    const float* r2W  = (const float*)d_in[8];
    const float* r2b  = (const float*)d_in[9];
    const float* kW   = (const float*)d_in[10];
    const float* kb   = (const float*)d_in[11];
    const float* bW   = (const float*)d_in[12];
    const float* bb   = (const float*)d_in[13];
    const float* l1W  = (const float*)d_in[14];
    const float* l1b  = (const float*)d_in[15];
    const float* l2W  = (const float*)d_in[16];
    const float* l2b  = (const float*)d_in[17];

    float* ws = (float*)d_ws;
    float* h2buf   = ws;                                  // NBL*KH f32
    float* biasbuf = h2buf + (size_t)NBL*KH;              // NBL*BCH f32
    float* h1buf   = biasbuf + (size_t)NBL*BCH;           // BB*KH*LSEG f32
    f16*   h2h     = (f16*)(h1buf + (size_t)BB*KH*LSEG);  // NBL*KH f16
    f16*   bufA    = h2h + (size_t)NBL*KH;                // BB*INNER*TT f16 each
    f16*   bufB    = bufA + (size_t)BB*INNER*TT;
    f16*   bufC    = bufB + (size_t)BB*INNER*TT;
    f16*   kbuf    = bufC + (size_t)BB*INNER*TT;          // NBL*RPL f16

    k_fc<<<BB*TT/256*2, 256, 0, stream>>>(x, fcW, fcb, bufA);

    for (int n = 0; n < 2; ++n) {
        k_h1<<<BB*8, 256, 0, stream>>>(c, inpW + (size_t)n*KH*COND*5, inpb + n*KH, h1buf);
        k_h2t<<<BB, 256, 0, stream>>>(h1buf,
            r1W + n*KH*KH, r1b + n*KH,
            r2W + n*KH*KH, r2b + n*KH, h2buf, h2h);
        f16* pin = (n == 0) ? bufA : bufB;
        f16* s0  = (n == 0) ? bufB : bufC;
        f16* s1  = (n == 0) ? bufC : bufA;
        f16* cin = pin;
        for (int i = 0; i < LAYERS; ++i) {
            int gblocks = (i == 0) ? (768 + (BB*BCH)/256) : 768;
            k_gen<<<gblocks, 256, 0, stream>>>(
                kW + ((size_t)n*KCH + (size_t)i*RPL)*KH,
                kb + (size_t)n*KCH + (size_t)i*RPL,
                h2h, kbuf,
                (i == 0) ? (bW + (size_t)n*BCH*KH) : nullptr,
                bb + (size_t)n*BCH,
                biasbuf, h2buf);
            f16* cout_ = (i % 2 == 0) ? s0 : s1;
            switch (i) {
                case 0: k_lvc<1> <<<BB*LSEG*4, 256, 0, stream>>>(cin, kbuf, biasbuf, cout_, i); break;
                case 1: k_lvc<2> <<<BB*LSEG*4, 256, 0, stream>>>(cin, kbuf, biasbuf, cout_, i); break;
                case 2: k_lvc<4> <<<BB*LSEG*4, 256, 0, stream>>>(cin, kbuf, biasbuf, cout_, i); break;
                case 3: k_lvc<8> <<<BB*LSEG*4, 256, 0, stream>>>(cin, kbuf, biasbuf, cout_, i); break;
                case 4: k_lvc<16><<<BB*LSEG*4, 256, 0, stream>>>(cin, kbuf, biasbuf, cout_, i); break;
            }
            cin = cout_;
        }
    }
    k_head<<<BB*TT/256, 256, 0, stream>>>(bufB, bufC, l1W, l1b, l2W, l2b, (float*)d_out);
}

// Round 4
// 1897.642 us; speedup vs baseline: 3.9345x; 1.0404x over previous
//
#include <hip/hip_runtime.h>
#include <math.h>

// ---------------- problem constants ----------------
#define BB     2
#define LSEG   64
#define HOP    256
#define TT     (LSEG*HOP)      // 16384
#define IN_CH  101
#define INNER  128
#define COND   81
#define LAYERS 5
#define KTAP   3
#define KH     64
#define COUT   256             // 2*INNER
#define RPL    (INNER*COUT*KTAP)   // 98304 rows per layer
#define KCH    (RPL*LAYERS)        // 491520
#define BCH    (COUT*LAYERS)       // 1280
#define NBL    (BB*LSEG)           // 128
#define XS     36                  // padded LDS row stride (f16) - bank stride 18

typedef _Float16 f16;
typedef _Float16 f16x2 __attribute__((ext_vector_type(2)));
typedef _Float16 f16x8 __attribute__((ext_vector_type(8)));
typedef float    f32x4 __attribute__((ext_vector_type(4)));

// ---------------- fc: h = fc_W @ x + fc_b -> f16 activations ----------------
__global__ __launch_bounds__(256) void k_fc(const float* __restrict__ x,
                                            const float* __restrict__ W,
                                            const float* __restrict__ bias,
                                            f16* __restrict__ out) {
    int half = blockIdx.x & 1;
    int g = (blockIdx.x >> 1)*256 + threadIdx.x;   // over BB*TT
    int b = g / TT, t = g % TT;
    float xv[IN_CH];
    const float* xp = x + (size_t)b*IN_CH*TT + t;
#pragma unroll
    for (int c = 0; c < IN_CH; ++c) xv[c] = xp[(size_t)c*TT];
    f16* op = out + (size_t)b*INNER*TT + t;
    int o0 = half*64;
    for (int o = o0; o < o0 + 64; ++o) {
        const float* wr = W + o*IN_CH;
        float a0 = bias[o], a1 = 0.f, a2 = 0.f, a3 = 0.f;
#pragma unroll
        for (int c = 0; c + 3 < IN_CH; c += 4) {
            a0 += wr[c]*xv[c]; a1 += wr[c+1]*xv[c+1];
            a2 += wr[c+2]*xv[c+2]; a3 += wr[c+3]*xv[c+3];
        }
        a0 += wr[100]*xv[100];
        op[(size_t)o*TT] = (f16)((a0+a1)+(a2+a3));
    }
}

// ---------------- predictor stage 1: h1 = lrelu(conv5(c)) ----------------
__global__ __launch_bounds__(256) void k_h1(const float* __restrict__ cc,
                                            const float* __restrict__ iW,
                                            const float* __restrict__ ib,
                                            float* __restrict__ h1buf) {
    int og = blockIdx.x & 7;
    int b  = blockIdx.x >> 3;
    __shared__ float cL[COND*LSEG];
    __shared__ float wL[8*COND*5];
    int tid = threadIdx.x;
    for (int idx = tid; idx < COND*LSEG; idx += 256)
        cL[idx] = cc[(size_t)b*COND*LSEG + idx];
    const float* wsrc = iW + (size_t)og*8*COND*5;
    for (int idx = tid; idx < 8*COND*5; idx += 256)
        wL[idx] = wsrc[idx];
    __syncthreads();
#pragma unroll
    for (int rep = 0; rep < 2; ++rep) {
        int idx = rep*256 + tid;
        int ol = idx >> 6, l = idx & 63;
        int o  = og*8 + ol;
        float acc = ib[o];
        const float* wrow = wL + ol*COND*5;
        for (int i = 0; i < COND; ++i) {
            const float* crow = cL + i*LSEG;
            const float* w5 = wrow + i*5;
#pragma unroll
            for (int k = 0; k < 5; ++k) {
                int ll = l + k - 2;
                if (ll >= 0 && ll < LSEG) acc += crow[ll]*w5[k];
            }
        }
        h1buf[((size_t)b*KH + o)*LSEG + l] = acc >= 0.f ? acc : 0.1f*acc;
    }
}

// ---------------- predictor stage 2: h2 (f32 for bias head, f16 for k_gen) ----------------
__global__ __launch_bounds__(256) void k_h2t(const float* __restrict__ h1buf,
                                             const float* __restrict__ r1W,
                                             const float* __restrict__ r1b,
                                             const float* __restrict__ r2W,
                                             const float* __restrict__ r2b,
                                             float* __restrict__ h2buf,
                                             f16* __restrict__ h2h) {
    int b = blockIdx.x;
    __shared__ float h1L[KH*LSEG];
    __shared__ float t1L[KH*LSEG];
    __shared__ float wL[KH*KH];
    int tid = threadIdx.x;
    for (int idx = tid; idx < KH*LSEG; idx += 256)
        h1L[idx] = h1buf[(size_t)b*KH*LSEG + idx];
    for (int idx = tid; idx < KH*KH; idx += 256)
        wL[idx] = r1W[idx];
    __syncthreads();
#pragma unroll
    for (int rep = 0; rep < 16; ++rep) {
        int idx = rep*256 + tid;
        int o = idx >> 6, l = idx & 63;
        float acc = r1b[o];
        const float* wr = wL + o*KH;
#pragma unroll
        for (int i = 0; i < KH; ++i) acc += wr[i]*h1L[i*LSEG + l];
        t1L[idx] = acc >= 0.f ? acc : 0.1f*acc;
    }
    __syncthreads();
    for (int idx = tid; idx < KH*KH; idx += 256)
        wL[idx] = r2W[idx];
    __syncthreads();
#pragma unroll
    for (int rep = 0; rep < 16; ++rep) {
        int idx = rep*256 + tid;
        int o = idx >> 6, l = idx & 63;
        float acc = r2b[o];
        const float* wr = wL + o*KH;
#pragma unroll
        for (int i = 0; i < KH; ++i) acc += wr[i]*t1L[i*LSEG + l];
        float h2 = h1L[o*LSEG + l] + acc;
        h2buf[((size_t)b*LSEG + l)*KH + o] = h2;           // [bl][o] f32
        h2h  [((size_t)b*LSEG + l)*KH + o] = (f16)h2;      // [bl][o] f16
    }
}

// ---------------- bias head (separate tiny kernel, once per n-block) ----------------
__global__ __launch_bounds__(256) void k_biash(const float* __restrict__ bW,
                                               const float* __restrict__ bb,
                                               const float* __restrict__ h2buf,
                                               float* __restrict__ biasbuf) {
    int tg = blockIdx.x*256 + threadIdx.x;       // 0..2559
    int b  = __builtin_amdgcn_readfirstlane(tg / BCH);
    int rb = tg % BCH;
    float w[KH];
    const float4* wp = (const float4*)(bW + (size_t)rb*KH);
#pragma unroll
    for (int q = 0; q < KH/4; ++q) {
        float4 v = wp[q];
        w[4*q] = v.x; w[4*q+1] = v.y; w[4*q+2] = v.z; w[4*q+3] = v.w;
    }
    float bv = bb[rb];
    for (int l = 0; l < LSEG; ++l) {
        const float* h2 = h2buf + ((size_t)b*LSEG + l)*KH;
        float a0 = bv, a1 = 0.f, a2 = 0.f, a3 = 0.f;
#pragma unroll
        for (int j = 0; j < KH; j += 4) {
            a0 += w[j]*h2[j]; a1 += w[j+1]*h2[j+1];
            a2 += w[j+2]*h2[j+2]; a3 += w[j+3]*h2[j+3];
        }
        biasbuf[((size_t)b*LSEG + l)*BCH + rb] = (a0+a1)+(a2+a3);
    }
}

// ---------------- kernel generation (f16, MFMA layout), software-pipelined h2 ----
// kbuf[bl][o'][kk'] f16, o' = gate-interleave(o), kk' = tap*128 + c
// grid: 768 = (tap 0..2) x (o 0..255); threads = (blh 0..1) x (c 0..127)
__global__ __launch_bounds__(256) void k_gen(const float* __restrict__ kW,
                                             const float* __restrict__ kb,
                                             const f16*   __restrict__ h2h,
                                             f16*         __restrict__ kbuf) {
    int tap = blockIdx.x >> 8;          // 0..2
    int o   = blockIdx.x & 255;
    int c   = threadIdx.x & 127;
    int blh = threadIdx.x >> 7;         // bl-half (wave-uniform)
    int r   = (c*COUT + o)*KTAP + tap;
    f16x2 wh[32];
    const float4* wp = (const float4*)(kW + (size_t)r*KH);
#pragma unroll
    for (int q = 0; q < 16; ++q) {
        float4 v = wp[q];
        wh[2*q]   = f16x2{(f16)v.x, (f16)v.y};
        wh[2*q+1] = f16x2{(f16)v.z, (f16)v.w};
    }
    float kbv = kb[r];
    int op = (o < 128) ? 2*o : 2*(o-128) + 1;
    size_t obase = (size_t)op*384 + (size_t)tap*128 + c;
    int bl0 = blh*64, bl1 = bl0 + 64;
    // software pipeline: scalar-prefetch next h2 row while computing current
    const uint4* h2q = (const uint4*)(h2h + (size_t)bl0*KH);   // 8 uint4 per row
    uint4 cur[8];
#pragma unroll
    for (int q = 0; q < 8; ++q) cur[q] = h2q[q];
    for (int bl = bl0; bl < bl1; ++bl) {
        int nbl = (bl + 1 < bl1) ? bl + 1 : bl;
        const uint4* nq = (const uint4*)(h2h + (size_t)nbl*KH);
        uint4 nxt[8];
#pragma unroll
        for (int q = 0; q < 8; ++q) nxt[q] = nq[q];
        float a0 = kbv, a1 = 0.f, a2 = 0.f, a3 = 0.f;
#pragma unroll
        for (int q = 0; q < 8; ++q) {
            uint4 u = cur[q];
            a0 = __builtin_amdgcn_fdot2(wh[4*q],   __builtin_bit_cast(f16x2, u.x), a0, false);
            a1 = __builtin_amdgcn_fdot2(wh[4*q+1], __builtin_bit_cast(f16x2, u.y), a1, false);
            a2 = __builtin_amdgcn_fdot2(wh[4*q+2], __builtin_bit_cast(f16x2, u.z), a2, false);
            a3 = __builtin_amdgcn_fdot2(wh[4*q+3], __builtin_bit_cast(f16x2, u.w), a3, false);
        }
        kbuf[(size_t)bl*RPL + obase] = (f16)((a0+a1)+(a2+a3));
#pragma unroll
        for (int q = 0; q < 8; ++q) cur[q] = nxt[q];
    }
}

// ---------------- LVC layer via MFMA + fused gating (padded LDS, fewer barriers) ----
// grid = BB*LSEG*4; WG (b,l,oq) computes C[64 o' x 256 t] for one (b,l)
template<int DIL>
__global__ __launch_bounds__(256) void k_lvc(const f16* __restrict__ xin,
                                             const f16* __restrict__ kbuf,
                                             const float* __restrict__ biasbuf,
                                             f16* __restrict__ xout,
                                             int layerIdx) {
    constexpr int WIN = 256 + 2*DIL;
    int wg  = blockIdx.x;
    int o0  = (wg & 3)*64;
    int l   = (wg >> 2) & 63;
    int b   = wg >> 8;
    int bl  = b*LSEG + l;
    int tid = threadIdx.x;
    int w   = tid >> 6;
    int lane = tid & 63;
    int quad = lane >> 4;
    int n16  = lane & 15;
    int wo = (w & 1)*32;
    int wt = (w >> 1)*128;

    __shared__ f16 As[3*64*XS];        // [tap][o'_local][kk 32] padded
    __shared__ f16 xwin[288*XS];       // [tw][c] padded

    const float* bias_l = biasbuf + (size_t)bl*BCH + layerIdx*COUT;
    f32x4 acc[2][8];
#pragma unroll
    for (int j = 0; j < 2; ++j) {
        int g0 = (o0 + wo + j*16 + quad*4) >> 1;
        f32x4 ini;
        ini[0] = bias_l[g0];       ini[1] = bias_l[g0 + 128];
        ini[2] = bias_l[g0 + 1];   ini[3] = bias_l[g0 + 1 + 128];
#pragma unroll
        for (int tt = 0; tt < 8; ++tt) acc[j][tt] = ini;
    }

    const f16* xb = xin + (size_t)b*INNER*TT;
    const f16* kbl = kbuf + (size_t)bl*RPL + (size_t)o0*384;
    int o_l = tid >> 2, q4 = tid & 3;

    for (int cb = 0; cb < 4; ++cb) {
        // stage x window (transposed, padded) + all 3 A-tap chunks; ONE barrier
        for (int idx = tid; idx < 32*WIN; idx += 256) {
            int c  = idx / WIN;                  // div by constant -> magic mul
            int tw = idx - c*WIN;
            int gt = l*256 - DIL + tw;
            f16 v = (gt >= 0 && gt < TT) ? xb[(size_t)(cb*32 + c)*TT + gt] : (f16)0.f;
            xwin[tw*XS + c] = v;
        }
#pragma unroll
        for (int tap = 0; tap < 3; ++tap) {
            f16x8 v = *(const f16x8*)&kbl[(size_t)o_l*384 + tap*128 + cb*32 + q4*8];
            *(f16x8*)&As[(tap*64 + o_l)*XS + q4*8] = v;
        }
        __syncthreads();
#pragma unroll
        for (int tap = 0; tap < 3; ++tap) {
            f16x8 af0 = *(const f16x8*)&As[(tap*64 + wo + n16)*XS + quad*8];
            f16x8 af1 = *(const f16x8*)&As[(tap*64 + wo + 16 + n16)*XS + quad*8];
#pragma unroll
            for (int tt = 0; tt < 8; ++tt) {
                int trow = wt + tt*16 + n16 + tap*DIL;
                f16x8 bf = *(const f16x8*)&xwin[trow*XS + quad*8];
                acc[0][tt] = __builtin_amdgcn_mfma_f32_16x16x32_f16(af0, bf, acc[0][tt], 0, 0, 0);
                acc[1][tt] = __builtin_amdgcn_mfma_f32_16x16x32_f16(af1, bf, acc[1][tt], 0, 0, 0);
            }
        }
        __syncthreads();
    }
    f16* ob = xout + (size_t)b*INNER*TT + l*256;
#pragma unroll
    for (int j = 0; j < 2; ++j) {
        int g0 = (o0 + wo + j*16 + quad*4) >> 1;
#pragma unroll
        for (int tt = 0; tt < 8; ++tt) {
            int tloc = wt + tt*16 + n16;
            f32x4 a = acc[j][tt];
            float s0  = 1.f/(1.f + __expf(-a[0]));
            float th0 = 2.f/(1.f + __expf(-2.f*a[1])) - 1.f;
            float s1  = 1.f/(1.f + __expf(-a[2]));
            float th1 = 2.f/(1.f + __expf(-2.f*a[3])) - 1.f;
            ob[(size_t)g0*TT + tloc]     = (f16)(s0*th0);
            ob[(size_t)(g0+1)*TT + tloc] = (f16)(s1*th1);
        }
    }
}

// ---------------- head: wave-uniform o-ranges -> scalar W1 loads ----------------
// grid = BB*TT/64 = 512; block: 64 t, 4 waves; wave w: o in [w*32, w*32+32)
__global__ __launch_bounds__(256) void k_head(const f16* __restrict__ y0,
                                              const f16* __restrict__ y1,
                                              const float* __restrict__ W1,
                                              const float* __restrict__ b1,
                                              const float* __restrict__ W2,
                                              const float* __restrict__ b2,
                                              float* __restrict__ out) {
    int b    = blockIdx.x >> 8;
    int tseg = (blockIdx.x & 255)*64;
    int tid  = threadIdx.x;
    int w    = tid >> 6;
    int lane = tid & 63;
    int t    = tseg + lane;
    __shared__ float red[4][64];

    float h[INNER];
    const f16* p0 = y0 + (size_t)b*INNER*TT + t;
    const f16* p1 = y1 + (size_t)b*INNER*TT + t;
#pragma unroll
    for (int c = 0; c < INNER; ++c) {
        float v = (float)p0[(size_t)c*TT] + (float)p1[(size_t)c*TT];
        h[c] = v > 0.f ? v : 0.f;
    }
    float part = 0.f;
    int oBase = w*32;
    for (int oi = 0; oi < 32; ++oi) {
        int o = oBase + oi;                      // wave-uniform
        const float* wr = W1 + o*INNER;          // -> s_load
        float z0 = b1[o], z1 = 0.f, z2 = 0.f, z3 = 0.f;
#pragma unroll
        for (int c = 0; c < INNER; c += 4) {
            z0 += wr[c]*h[c];   z1 += wr[c+1]*h[c+1];
            z2 += wr[c+2]*h[c+2]; z3 += wr[c+3]*h[c+3];
        }
        float z = (z0+z1)+(z2+z3);
        z = z > 0.f ? z : 0.f;
        part += W2[o]*z;
    }
    red[w][lane] = part;
    __syncthreads();
    if (w == 0) {
        float acc = b2[0] + red[0][lane] + red[1][lane] + red[2][lane] + red[3][lane];
        out[(size_t)b*TT + t] = acc;
    }
}

extern "C" void kernel_launch(void* const* d_in, const int* in_sizes, int n_in,
                              void* d_out, int out_size, void* d_ws, size_t ws_size,
                              hipStream_t stream) {
    const float* x    = (const float*)d_in[0];
    const float* c    = (const float*)d_in[1];
    const float* fcW  = (const float*)d_in[2];
    const float* fcb  = (const float*)d_in[3];
    const float* inpW = (const float*)d_in[4];
    const float* inpb = (const float*)d_in[5];
    const float* r1W  = (const float*)d_in[6];
    const float* r1b  = (const float*)d_in[7];
    const float* r2W  = (const float*)d_in[8];
    const float* r2b  = (const float*)d_in[9];
    const float* kW   = (const float*)d_in[10];
    const float* kb   = (const float*)d_in[11];
    const float* bW   = (const float*)d_in[12];
    const float* bb   = (const float*)d_in[13];
    const float* l1W  = (const float*)d_in[14];
    const float* l1b  = (const float*)d_in[15];
    const float* l2W  = (const float*)d_in[16];
    const float* l2b  = (const float*)d_in[17];

    float* ws = (float*)d_ws;
    float* h2buf   = ws;                                  // NBL*KH f32
    float* biasbuf = h2buf + (size_t)NBL*KH;              // NBL*BCH f32
    float* h1buf   = biasbuf + (size_t)NBL*BCH;           // BB*KH*LSEG f32
    f16*   h2h     = (f16*)(h1buf + (size_t)BB*KH*LSEG);  // NBL*KH f16
    f16*   bufA    = h2h + (size_t)NBL*KH;                // BB*INNER*TT f16 each
    f16*   bufB    = bufA + (size_t)BB*INNER*TT;
    f16*   bufC    = bufB + (size_t)BB*INNER*TT;
    f16*   kbuf    = bufC + (size_t)BB*INNER*TT;          // NBL*RPL f16

    k_fc<<<BB*TT/256*2, 256, 0, stream>>>(x, fcW, fcb, bufA);

    for (int n = 0; n < 2; ++n) {
        k_h1<<<BB*8, 256, 0, stream>>>(c, inpW + (size_t)n*KH*COND*5, inpb + n*KH, h1buf);
        k_h2t<<<BB, 256, 0, stream>>>(h1buf,
            r1W + n*KH*KH, r1b + n*KH,
            r2W + n*KH*KH, r2b + n*KH, h2buf, h2h);
        k_biash<<<(BB*BCH)/256, 256, 0, stream>>>(bW + (size_t)n*BCH*KH, bb + n*BCH,
                                                  h2buf, biasbuf);
        f16* pin = (n == 0) ? bufA : bufB;
        f16* s0  = (n == 0) ? bufB : bufC;
        f16* s1  = (n == 0) ? bufC : bufA;
        f16* cin = pin;
        for (int i = 0; i < LAYERS; ++i) {
            k_gen<<<768, 256, 0, stream>>>(
                kW + ((size_t)n*KCH + (size_t)i*RPL)*KH,
                kb + (size_t)n*KCH + (size_t)i*RPL,
                h2h, kbuf);
            f16* cout_ = (i % 2 == 0) ? s0 : s1;
            switch (i) {
                case 0: k_lvc<1> <<<BB*LSEG*4, 256, 0, stream>>>(cin, kbuf, biasbuf, cout_, i); break;
                case 1: k_lvc<2> <<<BB*LSEG*4, 256, 0, stream>>>(cin, kbuf, biasbuf, cout_, i); break;
                case 2: k_lvc<4> <<<BB*LSEG*4, 256, 0, stream>>>(cin, kbuf, biasbuf, cout_, i); break;
                case 3: k_lvc<8> <<<BB*LSEG*4, 256, 0, stream>>>(cin, kbuf, biasbuf, cout_, i); break;
                case 4: k_lvc<16><<<BB*LSEG*4, 256, 0, stream>>>(cin, kbuf, biasbuf, cout_, i); break;
            }
            cin = cout_;
        }
    }
    k_head<<<BB*TT/64, 256, 0, stream>>>(bufB, bufC, l1W, l1b, l2W, l2b, (float*)d_out);
}